// Round 2
// baseline (199.810 us; speedup 1.0000x reference)
//
#include <hip/hip_runtime.h>
#include <hip/hip_bf16.h>
#include <math.h>

// Problem constants
#define Bc  32
#define Nn  512
#define Dd  256
#define Hh  8
#define HDd 32
#define Ee  16384
#define KT  64    // attention k-tile

typedef __attribute__((ext_vector_type(8))) short bf16x8;
typedef __attribute__((ext_vector_type(4))) float f32x4;

__device__ inline ushort f2bf(float x){
  union { float f; unsigned u; } v; v.f = x;
  return (ushort)((v.u + 0x7fff + ((v.u >> 16) & 1)) >> 16);   // RNE
}

// async global->LDS DMA, 16B per lane; LDS dest = wave-uniform base + lane*16
__device__ __forceinline__ void load_lds16(const void* g, void* l){
  __builtin_amdgcn_global_load_lds((const __attribute__((address_space(1))) unsigned int*)g,
                                   (__attribute__((address_space(3))) unsigned int*)l, 16, 0, 0);
}

// pack 8 f32 -> bf16x8 via v_cvt_pk_bf16_f32 (RNE, matches f2bf)
__device__ __forceinline__ bf16x8 pack8(f32x4 lo, f32x4 hi){
  union { bf16x8 v; unsigned u[4]; } r;
  asm("v_cvt_pk_bf16_f32 %0, %1, %2" : "=v"(r.u[0]) : "v"(lo[0]), "v"(lo[1]));
  asm("v_cvt_pk_bf16_f32 %0, %1, %2" : "=v"(r.u[1]) : "v"(lo[2]), "v"(lo[3]));
  asm("v_cvt_pk_bf16_f32 %0, %1, %2" : "=v"(r.u[2]) : "v"(hi[0]), "v"(hi[1]));
  asm("v_cvt_pk_bf16_f32 %0, %1, %2" : "=v"(r.u[3]) : "v"(hi[2]), "v"(hi[3]));
  return r.v;
}

// ---------------- graph prep: dense normalized adjacency ----------------

__global__ __launch_bounds__(256) void k_count(const int* __restrict__ ei, int* __restrict__ count){
  int e = blockIdx.x*256 + threadIdx.x;
  if (e < Ee) atomicAdd(&count[ei[Ee + e]], 1);
}

__global__ __launch_bounds__(256) void k_scatter(const int* __restrict__ ei, const int* __restrict__ count,
                                                 float* __restrict__ S){
  int e = blockIdx.x*256 + threadIdx.x;
  if (e < Ee){
    int s = ei[e], d = ei[Ee + e];
    float w = rsqrtf((1.0f + (float)count[s]) * (1.0f + (float)count[d]));
    atomicAdd(&S[d*Nn + s], w);   // duplicates accumulate, matches ref
  }
}

// add self-loop diagonal, convert to bf16
__global__ __launch_bounds__(256) void k_sbf(const float* __restrict__ S, const int* __restrict__ count,
                                             ushort* __restrict__ Sb){
  int base = (blockIdx.x*256 + threadIdx.x)*4;
  #pragma unroll
  for (int j = 0; j < 4; j++){
    int i = base + j;
    int d = i >> 9, s = i & (Nn-1);
    float v = S[i] + ((d == s) ? 1.0f/(1.0f + (float)count[d]) : 0.0f);
    Sb[i] = f2bf(v);
  }
}

// ---------------- W transpose+convert (z<4) + mask bit-pack (z==4) ----------------
__global__ __launch_bounds__(256) void k_wt(const float* __restrict__ Wq, const float* __restrict__ Wk,
                                            const float* __restrict__ Wv, const float* __restrict__ Wo,
                                            const int* __restrict__ mask,
                                            ushort* __restrict__ Wtq, ushort* __restrict__ Wtk,
                                            ushort* __restrict__ Wtv, ushort* __restrict__ Wto,
                                            ushort* __restrict__ Mbits){
  __shared__ float Ls[64][65];
  int mat = blockIdx.z;
  if (mat == 4){
    int bid = blockIdx.y*4 + blockIdx.x;        // 0..15
    int w0 = bid*1024 + threadIdx.x*4;
    #pragma unroll
    for (int j = 0; j < 4; j++){
      int w = w0 + j;
      int row = w >> 5, c0 = (w & 31) << 4;
      unsigned bits = 0;
      #pragma unroll
      for (int i = 0; i < 16; i++)
        bits |= (mask[(size_t)row*Nn + c0 + i] != 0 ? 1u : 0u) << i;
      Mbits[w] = (ushort)bits;
    }
    return;
  }
  const float* Wsrc = (mat==0)?Wq:(mat==1)?Wk:(mat==2)?Wv:Wo;
  ushort* Wt = (mat==0)?Wtq:(mat==1)?Wtk:(mat==2)?Wtv:Wto;
  int k0 = blockIdx.x*64, n0 = blockIdx.y*64;
  int t = threadIdx.x;
  {
    int r = t >> 2, c4 = (t & 3)*16;
    #pragma unroll
    for (int j = 0; j < 16; j += 4)
      *(float4*)&Ls[r][c4+j] = *(const float4*)(Wsrc + (size_t)(k0+r)*Dd + n0 + c4 + j);
  }
  __syncthreads();
  int nr = t >> 2, kc = (t & 3)*16;
  ushort hb[16];
  #pragma unroll
  for (int j = 0; j < 16; j++) hb[j] = f2bf(Ls[kc+j][nr]);
  size_t dst = (size_t)(n0+nr)*Dd + k0 + kc;
  *(int4*)(Wt + dst)     = ((int4*)hb)[0];
  *(int4*)(Wt + dst + 8) = ((int4*)hb)[1];
}

// ============ shared GEMM pieces (bf16 A path: 128x64 tile, K-chunk 64) ============
// LDS layout: unpadded [row][64] ushorts; chunk slot s of row r holds GLOBAL chunk
// s^(r&7) (swizzle applied on the global offset; DMA's LDS side is linear).

#define STAGE_A128(srcp, ldK)                                          \
  _Pragma("unroll")                                                    \
  for (int call = 0; call < 4; call++){                                \
    int id_ = t + call*256;                                            \
    int row_ = id_ >> 3, c8_ = (id_ & 7) ^ (row_ & 7);                 \
    load_lds16((srcp) + (size_t)row_*(ldK) + c8_*8,                    \
               As + ((size_t)call*256 + wave*64)*8);                   \
  }

#define STAGE_B64(srcp, ldK)                                           \
  _Pragma("unroll")                                                    \
  for (int call = 0; call < 2; call++){                                \
    int id_ = t + call*256;                                            \
    int row_ = id_ >> 3, c8_ = (id_ & 7) ^ (row_ & 7);                 \
    load_lds16((srcp) + (size_t)row_*(ldK) + c8_*8,                    \
               Bs + ((size_t)call*256 + wave*64)*8);                   \
  }

#define GEMM_COMPUTE()                                                           \
  _Pragma("unroll")                                                              \
  for (int kk = 0; kk < 2; kk++){                                                \
    bf16x8 af[2];                                                                \
    _Pragma("unroll")                                                            \
    for (int r2 = 0; r2 < 2; r2++){                                              \
      int ra_ = wave*32 + r2*16 + l16;                                           \
      af[r2] = *(const bf16x8*)(As + ra_*64 + (((kk<<2)+g) ^ (ra_&7))*8);        \
    }                                                                            \
    _Pragma("unroll")                                                            \
    for (int nf = 0; nf < 4; nf++){                                              \
      int rb_ = nf*16 + l16;                                                     \
      bf16x8 bfr = *(const bf16x8*)(Bs + rb_*64 + (((kk<<2)+g) ^ (rb_&7))*8);    \
      _Pragma("unroll")                                                          \
      for (int r2 = 0; r2 < 2; r2++)                                             \
        acc[r2][nf] = __builtin_amdgcn_mfma_f32_16x16x32_bf16(af[r2], bfr, acc[r2][nf], 0, 0, 0); \
    }                                                                            \
  }

// XCD-aware decode for grid=1536 (agge): m0 fastest -> B-panel L2 reuse
#define DECODE_PAZ()                                                   \
  int bid = blockIdx.x;                                                \
  int xcd = bid & 7, j_ = bid >> 3;                                    \
  int z = xcd*12 + (j_ % 12);                                          \
  int rr_ = j_ / 12;                                                   \
  int m0 = (rr_ & 3)*128, n0 = (rr_ >> 2)*64;                          \
  int which = z >> 5, b = z & 31;

// ---------------- k_proj: T = X@W (no bias), X read DIRECTLY as f32 ----------------
// f32 A tile staged via global_load_lds (32KB, 16-chunk XOR swizzle), converted to
// bf16 fragments in-register (pack8). Replaces the separate k_xbf pass entirely.
// Output transposed Tt[b][ch][node].
__global__ __launch_bounds__(256) void k_proj(const float* __restrict__ qI, const float* __restrict__ kI,
                                              const float* __restrict__ vI,
                                              const ushort* __restrict__ Wtq, const ushort* __restrict__ Wtk,
                                              const ushort* __restrict__ Wtv,
                                              ushort* __restrict__ Ttq, ushort* __restrict__ Ttk,
                                              ushort* __restrict__ Ttv){
  __shared__ float  AsF[128*64];   // 32KB; epilogue aliases as Ts[64][136] ushorts
  __shared__ ushort Bs[64*64];     // 8KB

  // decode: n0 fastest so the 4 blocks sharing an A-panel are dispatch-adjacent (same XCD)
  int bid = blockIdx.x;
  int xcd = bid & 7, j_ = bid >> 3;          // j_ 0..191
  int zi = j_ >> 4, rr_ = j_ & 15;
  int z = xcd*12 + zi;
  int m0 = (rr_ >> 2)*128, n0 = (rr_ & 3)*64;
  int which = z >> 5, b = z & 31;

  const float* X = (which==0)?qI:(which==1)?kI:vI;
  const ushort* Wt = (which==0)?Wtq:(which==1)?Wtk:Wtv;
  ushort*       Tt = (which==0)?Ttq:(which==1)?Ttk:Ttv;

  int t = threadIdx.x, wave = t >> 6, lane = t & 63;
  int g = lane >> 4, l16 = lane & 15;

  f32x4 acc[2][4] = {};

  for (int k0 = 0; k0 < Dd; k0 += 64){
    // A: 128 rows x 64 f32; 16 chunks/row of 16B; chunk slot p of row r holds
    // global chunk p^(r&15)  (swizzle on global src; DMA LDS side linear)
    #pragma unroll
    for (int call = 0; call < 8; call++){
      int id_ = t + call*256;
      int row_ = id_ >> 4, c16_ = (id_ & 15) ^ (row_ & 15);
      load_lds16(X + (size_t)(b*Nn + m0 + row_)*Dd + k0 + c16_*4,
                 AsF + ((size_t)call*256 + wave*64)*4);
    }
    #pragma unroll
    for (int call = 0; call < 2; call++){
      int id_ = t + call*256;
      int row_ = id_ >> 3, c8_ = (id_ & 7) ^ (row_ & 7);
      load_lds16(Wt + (size_t)(n0 + row_)*Dd + k0 + c8_*8,
                 (ushort*)Bs + ((size_t)call*256 + wave*64)*8);
    }
    __syncthreads();

    #pragma unroll
    for (int kk = 0; kk < 2; kk++){
      bf16x8 af[2];
      #pragma unroll
      for (int r2 = 0; r2 < 2; r2++){
        int ra_ = wave*32 + r2*16 + l16;
        int cb = (kk*4 + g)*2;
        f32x4 lo = *(const f32x4*)(AsF + ra_*64 + ((cb    ) ^ (ra_&15))*4);
        f32x4 hi = *(const f32x4*)(AsF + ra_*64 + ((cb + 1) ^ (ra_&15))*4);
        af[r2] = pack8(lo, hi);
      }
      #pragma unroll
      for (int nf = 0; nf < 4; nf++){
        int rb_ = nf*16 + l16;
        bf16x8 bfr = *(const bf16x8*)((const ushort*)Bs + rb_*64 + (((kk<<2)+g) ^ (rb_&7))*8);
        #pragma unroll
        for (int r2 = 0; r2 < 2; r2++)
          acc[r2][nf] = __builtin_amdgcn_mfma_f32_16x16x32_bf16(af[r2], bfr, acc[r2][nf], 0, 0, 0);
      }
    }
    __syncthreads();
  }

  // transposed epilogue via LDS: Ts[n_local][m_local], 64 x 128 (stride 136)
  ushort (*Ts)[136] = (ushort (*)[136])(void*)AsF;
  #pragma unroll
  for (int nf = 0; nf < 4; nf++)
    #pragma unroll
    for (int r2 = 0; r2 < 2; r2++)
      #pragma unroll
      for (int q4 = 0; q4 < 4; q4++)
        Ts[nf*16 + l16][wave*32 + r2*16 + g*4 + q4] = f2bf(acc[r2][nf][q4]);
  __syncthreads();
  #pragma unroll
  for (int i = 0; i < 4; i++){
    int id = t + i*256;
    int nr = id >> 4, mc = (id & 15)*8;
    *(int4*)(Tt + ((size_t)b*Dd + n0 + nr)*Nn + m0 + mc) = *(int4*)&Ts[nr][mc];
  }
}

// ---------------- k_agge: QKV = S @ T + bias
// Q -> head layout pre-scaled by 1/sqrt(32)*log2(e); K -> head layout; V -> Vt[b][ch][node]
__global__ __launch_bounds__(256) void k_agge(const ushort* __restrict__ Sb,
                                              const ushort* __restrict__ Ttq, const ushort* __restrict__ Ttk,
                                              const ushort* __restrict__ Ttv,
                                              const float* __restrict__ bq, const float* __restrict__ bk,
                                              const float* __restrict__ bv,
                                              ushort* __restrict__ Qh, ushort* __restrict__ Kh,
                                              ushort* __restrict__ Vt){
  __shared__ ushort LB[128*64 + 64*64];
  ushort* As = LB;
  ushort* Bs = LB + 128*64;

  DECODE_PAZ();
  const ushort* Tt  = (which==0)?Ttq:(which==1)?Ttk:Ttv;
  const float*  bia = (which==0)?bq:(which==1)?bk:bv;

  int t = threadIdx.x, wave = t >> 6, lane = t & 63;
  int g = lane >> 4, l16 = lane & 15;

  f32x4 acc[2][4] = {};

  for (int k0 = 0; k0 < Nn; k0 += 64){
    STAGE_A128(Sb + (size_t)m0*Nn + k0, Nn);
    STAGE_B64(Tt + ((size_t)b*Dd + n0)*Nn + k0, Nn);
    __syncthreads();
    GEMM_COMPUTE();
    __syncthreads();
  }

  const float qscale = 0.17677669529663687f * 1.4426950408889634f;  // 1/sqrt(32)*log2(e)

  if (which == 2){
    // V: bias then LDS-transpose -> Vt[(b*256 + channel)][node]
    ushort (*Ts)[136] = (ushort (*)[136])(void*)LB;
    #pragma unroll
    for (int nf = 0; nf < 4; nf++)
      #pragma unroll
      for (int r2 = 0; r2 < 2; r2++)
        #pragma unroll
        for (int q4 = 0; q4 < 4; q4++){
          int n = n0 + nf*16 + l16;
          Ts[nf*16 + l16][wave*32 + r2*16 + g*4 + q4] = f2bf(acc[r2][nf][q4] + bia[n]);
        }
    __syncthreads();
    #pragma unroll
    for (int i = 0; i < 4; i++){
      int id = t + i*256;
      int nr = id >> 4, mc = (id & 15)*8;
      *(int4*)(Vt + ((size_t)b*Dd + n0 + nr)*Nn + m0 + mc) = *(int4*)&Ts[nr][mc];
    }
  } else {
    ushort* out = (which==0) ? Qh : Kh;
    float sc = (which==0) ? qscale : 1.0f;
    #pragma unroll
    for (int nf = 0; nf < 4; nf++){
      #pragma unroll
      for (int r2 = 0; r2 < 2; r2++)
        #pragma unroll
        for (int q4 = 0; q4 < 4; q4++){
          int m = m0 + wave*32 + r2*16 + g*4 + q4;   // node
          int n = n0 + nf*16 + l16;                  // out channel
          float val = (acc[r2][nf][q4] + bia[n]) * sc;
          int h = n >> 5, hd = n & 31;
          out[((size_t)(b*Hh + h)*Nn + m)*HDd + hd] = f2bf(val);
        }
    }
  }
}

// ---------------- MFMA attention v3: swapped QK^T + T14 reg-prefetch of K/V/mask ----
// Per tile: write prefetched regs -> LDS, barrier, ISSUE next tile's global loads
// (latency hides under QK/exp/PV compute), compute, barrier. s_setprio(1) around the
// PV MFMA cluster (m191: +4-7% attn). launch_bounds(256,4): VGPR<=128, no spill risk
// (round 1 showed occupancy-insensitivity, so 4 blocks/CU is fine).
__global__ __launch_bounds__(256, 4) void k_attn(const ushort* __restrict__ Qg, const ushort* __restrict__ Kg,
                                              const ushort* __restrict__ Vt, const ushort* __restrict__ Mbits,
                                              ushort* __restrict__ xh){
  __shared__ ushort Ks[KT][40];        // K rows [k][hd]
  __shared__ ushort Vs[HDd][KT+8];     // V^T [hd][k]
  __shared__ ushort Ps[4][16][KT+8];   // per-wave P [q][k]

  int bx = blockIdx.x;
  int bh = bx & 255;
  int qt = bx >> 8;
  int b = bh >> 3, h = bh & 7;
  int t = threadIdx.x, wave = t >> 6, lane = t & 63;
  int g = lane >> 4, l16 = lane & 15;

  const ushort* Qp = Qg + (size_t)bh*Nn*HDd;
  const ushort* Kp = Kg + (size_t)bh*Nn*HDd;
  const ushort* Vp = Vt + (size_t)bh*HDd*Nn;

  int q0 = qt*64 + wave*16;
  bf16x8 qfrag = *(const bf16x8*)(Qp + (size_t)(q0 + l16)*HDd + g*8);
  const ushort* Mrow = Mbits + (size_t)(q0 + l16)*32;   // this lane's mask row

  bf16x8 ones;
  #pragma unroll
  for (int j = 0; j < 8; j++) ones[j] = (short)0x3F80;   // 1.0 bf16

  f32x4 Ofrag[2] = {{0,0,0,0},{0,0,0,0}};
  f32x4 rs = {0,0,0,0};

  // per-thread staging coords (K: 64x32 = 1 int4/thread; V: 32x64 = 1 int4/thread)
  int kr = t >> 2, kc = (t & 3)*8;
  int vr = t >> 3, vc = (t & 7)*8;
  const ushort* Ksrc = Kp + (size_t)kr*HDd + kc;
  const ushort* Vsrc = Vp + (size_t)vr*Nn + vc;

  int4 kreg = *(const int4*)Ksrc;          // tile 0
  int4 vreg = *(const int4*)Vsrc;
  uint2 mwv = *(const uint2*)Mrow;

  for (int kt = 0; kt < Nn; kt += KT){
    *(int4*)&Ks[kr][kc] = kreg;
    *(int4*)&Vs[vr][vc] = vreg;
    // pre-shift mask words by g*4 so per-(f,r) bit position is compile-time
    unsigned w0 = mwv.x >> (g*4), w1 = mwv.y >> (g*4);
    __syncthreads();

    if (kt + KT < Nn){                     // issue next tile's loads; waited at next
      kreg = *(const int4*)(Ksrc + (size_t)(kt + KT)*HDd);   // iteration's ds_write
      vreg = *(const int4*)(Vsrc + (kt + KT));
      mwv  = *(const uint2*)(Mrow + ((kt + KT) >> 4));
    }

    #pragma unroll
    for (int f = 0; f < KT/16; f++){
      bf16x8 kfrag = *(const bf16x8*)&Ks[f*16 + l16][g*8];
      unsigned wf = (f & 2) ? w1 : w0;
      f32x4 ci;
      #pragma unroll
      for (int r = 0; r < 4; r++){
        unsigned bit = (wf >> ((f & 1)*16 + r)) & 1u;          // v_bfe_u32
        ci[r] = __uint_as_float((bit - 1u) & 0xF149F2CAu);     // bit?0.0f:-1e30f
      }
      // swapped: A=K rows, B=Q rows -> D[k=f*16+g*4+r][q=l16]
      f32x4 s = __builtin_amdgcn_mfma_f32_16x16x32_bf16(kfrag, qfrag, ci, 0, 0, 0);
      float e0 = __builtin_exp2f(s[0]);
      float e1 = __builtin_exp2f(s[1]);
      float e2 = __builtin_exp2f(s[2]);
      float e3 = __builtin_exp2f(s[3]);
      unsigned p01, p23;
      asm("v_cvt_pk_bf16_f32 %0, %1, %2" : "=v"(p01) : "v"(e0), "v"(e1));
      asm("v_cvt_pk_bf16_f32 %0, %1, %2" : "=v"(p23) : "v"(e2), "v"(e3));
      uint2 pk; pk.x = p01; pk.y = p23;
      *(uint2*)&Ps[wave][l16][f*16 + g*4] = pk;                // single ds_write_b64
    }
    // no barrier: Ps is wave-private, lgkmcnt orders RAW

    __builtin_amdgcn_s_setprio(1);
    #pragma unroll
    for (int ks = 0; ks < KT/32; ks++){
      bf16x8 af = *(const bf16x8*)&Ps[wave][l16][ks*32 + g*8];
      rs = __builtin_amdgcn_mfma_f32_16x16x32_bf16(af, ones, rs, 0, 0, 0);  // row sums
      #pragma unroll
      for (int nt = 0; nt < 2; nt++){
        bf16x8 vf = *(const bf16x8*)&Vs[nt*16 + l16][ks*32 + g*8];
        Ofrag[nt] = __builtin_amdgcn_mfma_f32_16x16x32_bf16(af, vf, Ofrag[nt], 0, 0, 0);
      }
    }
    __builtin_amdgcn_s_setprio(0);
    __syncthreads();
  }

  float inv[4];
  #pragma unroll
  for (int r = 0; r < 4; r++) inv[r] = 1.0f / rs[r];

  #pragma unroll
  for (int nt = 0; nt < 2; nt++){
    #pragma unroll
    for (int r = 0; r < 4; r++){
      int row = q0 + g*4 + r;
      int col = h*HDd + nt*16 + l16;
      xh[((size_t)b*Nn + row)*Dd + col] = f2bf(Ofrag[nt][r] * inv[r]);
    }
  }
}

// ---------------- out-projection: C = x@Wo + bo, DMA-staged bf16 MFMA
__global__ __launch_bounds__(256) void k_gemm_o(const ushort* __restrict__ xh,
                                                const ushort* __restrict__ Wto,
                                                const float* __restrict__ bo, float* __restrict__ out){
  __shared__ ushort LB[128*64 + 64*64];
  ushort* As = LB;
  ushort* Bs = LB + 128*64;

  // XCD-aware: 512 blocks; each XCD owns 16 consecutive m-tiles complete
  int bid = blockIdx.x;
  int xcd = bid & 7, j_ = bid >> 3;            // j_ 0..63
  int m0 = (xcd*16 + (j_ >> 2))*128;
  int n0 = (j_ & 3)*64;

  int t = threadIdx.x, wave = t >> 6, lane = t & 63;
  int g = lane >> 4, l16 = lane & 15;

  f32x4 acc[2][4] = {};

  for (int k0 = 0; k0 < Dd; k0 += 64){
    STAGE_A128(xh + (size_t)m0*Dd + k0, Dd);
    STAGE_B64(Wto + (size_t)n0*Dd + k0, Dd);
    __syncthreads();
    GEMM_COMPUTE();
    __syncthreads();
  }

  #pragma unroll
  for (int nf = 0; nf < 4; nf++){
    #pragma unroll
    for (int r2 = 0; r2 < 2; r2++)
      #pragma unroll
      for (int q4 = 0; q4 < 4; q4++){
        int m = m0 + wave*32 + r2*16 + g*4 + q4;
        int n = n0 + nf*16 + l16;
        out[(size_t)m*Dd + n] = acc[r2][nf][q4] + bo[n];
      }
  }
}

// ---------------- launch ----------------
extern "C" void kernel_launch(void* const* d_in, const int* in_sizes, int n_in,
                              void* d_out, int out_size, void* d_ws, size_t ws_size,
                              hipStream_t stream){
  const float* query = (const float*)d_in[0];
  const float* key   = (const float*)d_in[1];
  const float* value = (const float*)d_in[2];
  const int*   ei    = (const int*)  d_in[3];
  const int*   mask  = (const int*)  d_in[4];
  const float* Wq = (const float*)d_in[5];
  const float* bq = (const float*)d_in[6];
  const float* Wk = (const float*)d_in[7];
  const float* bk = (const float*)d_in[8];
  const float* Wv = (const float*)d_in[9];
  const float* bv = (const float*)d_in[10];
  const float* Wo = (const float*)d_in[11];
  const float* bo = (const float*)d_in[12];

  char* ws = (char*)d_ws;
  size_t off = 0;
  auto alloc = [&](size_t bytes)->void*{
    void* p = ws + off;
    off = (off + bytes + 255) & ~(size_t)255;
    return p;
  };
  int*    count  = (int*)   alloc(Nn*4);              // contiguous with S (one memset)
  float*  S      = (float*) alloc((size_t)Nn*Nn*4);
  ushort* Sb     = (ushort*)alloc((size_t)Nn*Nn*2);
  ushort* Mbits  = (ushort*)alloc((size_t)Nn*32*2);
  ushort* Wtq    = (ushort*)alloc((size_t)Dd*Dd*2);
  ushort* Wtk    = (ushort*)alloc((size_t)Dd*Dd*2);
  ushort* Wtv    = (ushort*)alloc((size_t)Dd*Dd*2);
  ushort* Wto    = (ushort*)alloc((size_t)Dd*Dd*2);
  size_t tszb = (size_t)Bc*Nn*Dd*sizeof(ushort);
  ushort* Ttq = (ushort*)alloc(tszb);
  ushort* Ttk = (ushort*)alloc(tszb);
  ushort* Ttv = (ushort*)alloc(tszb);
  ushort* Qh  = (ushort*)alloc(tszb);
  ushort* Kh  = (ushort*)alloc(tszb);
  ushort* Vt  = (ushort*)alloc(tszb);
  ushort* xh  = (ushort*)alloc(tszb);

  hipMemsetAsync(count, 0, Nn*4 + (size_t)Nn*Nn*4, stream);   // count + S, contiguous

  k_count  <<<Ee/256, 256, 0, stream>>>(ei, count);
  k_scatter<<<Ee/256, 256, 0, stream>>>(ei, count, S);
  k_sbf    <<<Nn*Nn/1024, 256, 0, stream>>>(S, count, Sb);

  dim3 gw(4, 4, 5);   // z=0..3: weight transpose; z=4: mask bit-pack
  k_wt<<<gw, 256, 0, stream>>>(Wq, Wk, Wv, Wo, mask, Wtq, Wtk, Wtv, Wto, Mbits);

  k_proj<<<1536, 256, 0, stream>>>(query, key, value, Wtq, Wtk, Wtv, Ttq, Ttk, Ttv);
  k_agge<<<1536, 256, 0, stream>>>(Sb, Ttq, Ttk, Ttv, bq, bk, bv, Qh, Kh, Vt);

  k_attn<<<Bc*Hh*8, 256, 0, stream>>>(Qh, Kh, Vt, Mbits, xh);

  k_gemm_o<<<512, 256, 0, stream>>>(xh, Wto, bo, (float*)d_out);
}

// Round 3
// 189.743 us; speedup vs baseline: 1.0531x; 1.0531x over previous
//
#include <hip/hip_runtime.h>
#include <hip/hip_bf16.h>
#include <math.h>

// Problem constants
#define Bc  32
#define Nn  512
#define Dd  256
#define Hh  8
#define HDd 32
#define Ee  16384
#define KT  64    // attention k-tile

typedef __attribute__((ext_vector_type(8))) short bf16x8;
typedef __attribute__((ext_vector_type(4))) float f32x4;

__device__ inline ushort f2bf(float x){
  union { float f; unsigned u; } v; v.f = x;
  return (ushort)((v.u + 0x7fff + ((v.u >> 16) & 1)) >> 16);   // RNE
}

// async global->LDS DMA, 16B per lane; LDS dest = wave-uniform base + lane*16
__device__ __forceinline__ void load_lds16(const void* g, void* l){
  __builtin_amdgcn_global_load_lds((const __attribute__((address_space(1))) unsigned int*)g,
                                   (__attribute__((address_space(3))) unsigned int*)l, 16, 0, 0);
}

// pack 8 f32 -> bf16x8 via v_cvt_pk_bf16_f32 (RNE, matches f2bf)
__device__ __forceinline__ bf16x8 pack8(f32x4 lo, f32x4 hi){
  union { bf16x8 v; unsigned u[4]; } r;
  asm("v_cvt_pk_bf16_f32 %0, %1, %2" : "=v"(r.u[0]) : "v"(lo[0]), "v"(lo[1]));
  asm("v_cvt_pk_bf16_f32 %0, %1, %2" : "=v"(r.u[1]) : "v"(lo[2]), "v"(lo[3]));
  asm("v_cvt_pk_bf16_f32 %0, %1, %2" : "=v"(r.u[2]) : "v"(hi[0]), "v"(hi[1]));
  asm("v_cvt_pk_bf16_f32 %0, %1, %2" : "=v"(r.u[3]) : "v"(hi[2]), "v"(hi[3]));
  return r.v;
}

// ---------------- graph prep: dense normalized adjacency ----------------

__global__ __launch_bounds__(256) void k_count(const int* __restrict__ ei, int* __restrict__ count){
  int e = blockIdx.x*256 + threadIdx.x;
  if (e < Ee) atomicAdd(&count[ei[Ee + e]], 1);
}

// edges + self-loop diagonal (count is final here; k_count ran in a prior launch)
__global__ __launch_bounds__(256) void k_scatter(const int* __restrict__ ei, const int* __restrict__ count,
                                                 float* __restrict__ S){
  int e = blockIdx.x*256 + threadIdx.x;
  if (e < Ee){
    int s = ei[e], d = ei[Ee + e];
    float w = rsqrtf((1.0f + (float)count[s]) * (1.0f + (float)count[d]));
    atomicAdd(&S[d*Nn + s], w);   // duplicates accumulate, matches ref
  }
  if (e < Nn)
    atomicAdd(&S[e*Nn + e], 1.0f/(1.0f + (float)count[e]));   // self-loop
}

// ---------------- W transpose+convert (z<4) + mask bit-pack (z==4) ----------------
__global__ __launch_bounds__(256) void k_wt(const float* __restrict__ Wq, const float* __restrict__ Wk,
                                            const float* __restrict__ Wv, const float* __restrict__ Wo,
                                            const int* __restrict__ mask,
                                            ushort* __restrict__ Wtq, ushort* __restrict__ Wtk,
                                            ushort* __restrict__ Wtv, ushort* __restrict__ Wto,
                                            ushort* __restrict__ Mbits){
  __shared__ float Ls[64][65];
  int mat = blockIdx.z;
  if (mat == 4){
    int bid = blockIdx.y*4 + blockIdx.x;        // 0..15
    int w0 = bid*1024 + threadIdx.x*4;
    #pragma unroll
    for (int j = 0; j < 4; j++){
      int w = w0 + j;
      int row = w >> 5, c0 = (w & 31) << 4;
      unsigned bits = 0;
      #pragma unroll
      for (int i = 0; i < 16; i++)
        bits |= (mask[(size_t)row*Nn + c0 + i] != 0 ? 1u : 0u) << i;
      Mbits[w] = (ushort)bits;
    }
    return;
  }
  const float* Wsrc = (mat==0)?Wq:(mat==1)?Wk:(mat==2)?Wv:Wo;
  ushort* Wt = (mat==0)?Wtq:(mat==1)?Wtk:(mat==2)?Wtv:Wto;
  int k0 = blockIdx.x*64, n0 = blockIdx.y*64;
  int t = threadIdx.x;
  {
    int r = t >> 2, c4 = (t & 3)*16;
    #pragma unroll
    for (int j = 0; j < 16; j += 4)
      *(float4*)&Ls[r][c4+j] = *(const float4*)(Wsrc + (size_t)(k0+r)*Dd + n0 + c4 + j);
  }
  __syncthreads();
  int nr = t >> 2, kc = (t & 3)*16;
  ushort hb[16];
  #pragma unroll
  for (int j = 0; j < 16; j++) hb[j] = f2bf(Ls[kc+j][nr]);
  size_t dst = (size_t)(n0+nr)*Dd + k0 + kc;
  *(int4*)(Wt + dst)     = ((int4*)hb)[0];
  *(int4*)(Wt + dst + 8) = ((int4*)hb)[1];
}

// ============ 128x128-tile GEMM pieces: f32 A staged via DMA, bf16 B ============
// A: 128 rows x 64 f32 (32KB), 16 chunks/row of 16B; chunk slot p of row r holds
// global chunk p^(r&15). B: 128 rows x 64 bf16 (16KB), 8 chunks/row, slot p^(r&7).
// (swizzle applied on the GLOBAL offset; DMA's LDS side is linear.)

#define STAGE_AF32(srcp, ldK)                                           \
  _Pragma("unroll")                                                     \
  for (int call = 0; call < 8; call++){                                 \
    int id_ = t + call*256;                                             \
    int row_ = id_ >> 4, c16_ = (id_ & 15) ^ (row_ & 15);               \
    load_lds16((srcp) + (size_t)row_*(ldK) + c16_*4,                    \
               AsF + ((size_t)call*256 + wave*64)*4);                   \
  }

#define STAGE_B128(srcp, ldK)                                           \
  _Pragma("unroll")                                                     \
  for (int call = 0; call < 4; call++){                                 \
    int id_ = t + call*256;                                             \
    int row_ = id_ >> 3, c8_ = (id_ & 7) ^ (row_ & 7);                  \
    load_lds16((srcp) + (size_t)row_*(ldK) + c8_*8,                     \
               Bs + ((size_t)call*256 + wave*64)*8);                    \
  }

#define GEMM_COMPUTE_128()                                              \
  _Pragma("unroll")                                                     \
  for (int kk = 0; kk < 2; kk++){                                       \
    bf16x8 af[2];                                                       \
    _Pragma("unroll")                                                   \
    for (int r2 = 0; r2 < 2; r2++){                                     \
      int ra_ = wave*32 + r2*16 + l16;                                  \
      int cb_ = (kk*4 + g)*2;                                           \
      f32x4 lo_ = *(const f32x4*)(AsF + ra_*64 + ((cb_    ) ^ (ra_&15))*4); \
      f32x4 hi_ = *(const f32x4*)(AsF + ra_*64 + ((cb_ + 1) ^ (ra_&15))*4); \
      af[r2] = pack8(lo_, hi_);                                         \
    }                                                                   \
    _Pragma("unroll")                                                   \
    for (int nf = 0; nf < 8; nf++){                                     \
      int rb_ = nf*16 + l16;                                            \
      bf16x8 bfr = *(const bf16x8*)(Bs + rb_*64 + (((kk<<2)+g) ^ (rb_&7))*8); \
      _Pragma("unroll")                                                 \
      for (int r2 = 0; r2 < 2; r2++)                                    \
        acc[r2][nf] = __builtin_amdgcn_mfma_f32_16x16x32_bf16(af[r2], bfr, acc[r2][nf], 0, 0, 0); \
    }                                                                   \
  }

// XCD-aware decode, grid=768 (= 96 z-slices x 4 m-tiles x 2 n-tiles); each XCD
// owns 12 z-slices complete; same-z m/n siblings stay on the same XCD (L2 reuse)
#define DECODE_PA128()                                                  \
  int bid = blockIdx.x;                                                 \
  int xcd = bid & 7, j_ = bid >> 3;          /* 0..95 */                \
  int z = xcd*12 + (j_ % 12);                                           \
  int rr_ = j_ / 12;                         /* 0..7 */                 \
  int m0 = (rr_ >> 1)*128, n0 = (rr_ & 1)*128;                          \
  int which = z >> 5, b = z & 31;

// ---------------- k_proj: T = X@W (no bias), X read DIRECTLY as f32 ----------------
// 128x128 output tile; f32 A staged via DMA, converted in-register (pack8).
// Output transposed Tt[b][ch][node].
__global__ __launch_bounds__(256, 3) void k_proj(const float* __restrict__ qI, const float* __restrict__ kI,
                                              const float* __restrict__ vI,
                                              const ushort* __restrict__ Wtq, const ushort* __restrict__ Wtk,
                                              const ushort* __restrict__ Wtv,
                                              ushort* __restrict__ Ttq, ushort* __restrict__ Ttk,
                                              ushort* __restrict__ Ttv){
  __shared__ __align__(16) char LB[49152];    // 32KB f32 A + 16KB bf16 B
  float*  AsF = (float*)LB;
  ushort* Bs  = (ushort*)(LB + 32768);

  DECODE_PA128();
  const float* X = (which==0)?qI:(which==1)?kI:vI;
  const ushort* Wt = (which==0)?Wtq:(which==1)?Wtk:Wtv;
  ushort*       Tt = (which==0)?Ttq:(which==1)?Ttk:Ttv;

  int t = threadIdx.x, wave = t >> 6, lane = t & 63;
  int g = lane >> 4, l16 = lane & 15;

  f32x4 acc[2][8] = {};

  for (int k0 = 0; k0 < Dd; k0 += 64){
    STAGE_AF32(X + (size_t)(b*Nn + m0)*Dd + k0, Dd);
    STAGE_B128(Wt + (size_t)n0*Dd + k0, Dd);
    __syncthreads();
    GEMM_COMPUTE_128();
    __syncthreads();
  }

  // transposed epilogue via LDS: Ts[n_local][m_local], 128 x 128 (stride 136)
  ushort (*Ts)[136] = (ushort (*)[136])(void*)LB;
  #pragma unroll
  for (int nf = 0; nf < 8; nf++)
    #pragma unroll
    for (int r2 = 0; r2 < 2; r2++)
      #pragma unroll
      for (int q4 = 0; q4 < 4; q4++)
        Ts[nf*16 + l16][wave*32 + r2*16 + g*4 + q4] = f2bf(acc[r2][nf][q4]);
  __syncthreads();
  #pragma unroll
  for (int i = 0; i < 8; i++){
    int id = t + i*256;
    int nr = id >> 4, mc = (id & 15)*8;
    *(int4*)(Tt + ((size_t)b*Dd + n0 + nr)*Nn + m0 + mc) = *(int4*)&Ts[nr][mc];
  }
}

// ---------------- k_agge: QKV = S @ T + bias (S staged as raw f32; k_sbf deleted)
// Q -> head layout pre-scaled by 1/sqrt(32)*log2(e); K -> head layout; V -> Vt[b][ch][node]
__global__ __launch_bounds__(256, 3) void k_agge(const float* __restrict__ S,
                                              const ushort* __restrict__ Ttq, const ushort* __restrict__ Ttk,
                                              const ushort* __restrict__ Ttv,
                                              const float* __restrict__ bq, const float* __restrict__ bk,
                                              const float* __restrict__ bv,
                                              ushort* __restrict__ Qh, ushort* __restrict__ Kh,
                                              ushort* __restrict__ Vt){
  __shared__ __align__(16) char LB[49152];
  float*  AsF = (float*)LB;
  ushort* Bs  = (ushort*)(LB + 32768);

  DECODE_PA128();
  const ushort* Tt  = (which==0)?Ttq:(which==1)?Ttk:Ttv;
  const float*  bia = (which==0)?bq:(which==1)?bk:bv;

  int t = threadIdx.x, wave = t >> 6, lane = t & 63;
  int g = lane >> 4, l16 = lane & 15;

  f32x4 acc[2][8] = {};

  for (int k0 = 0; k0 < Nn; k0 += 64){
    STAGE_AF32(S + (size_t)m0*Nn + k0, Nn);
    STAGE_B128(Tt + ((size_t)b*Dd + n0)*Nn + k0, Nn);
    __syncthreads();
    GEMM_COMPUTE_128();
    __syncthreads();
  }

  const float qscale = 0.17677669529663687f * 1.4426950408889634f;  // 1/sqrt(32)*log2(e)

  if (which == 2){
    // V: bias then LDS-transpose -> Vt[(b*256 + channel)][node]
    ushort (*Ts)[136] = (ushort (*)[136])(void*)LB;
    #pragma unroll
    for (int nf = 0; nf < 8; nf++)
      #pragma unroll
      for (int r2 = 0; r2 < 2; r2++)
        #pragma unroll
        for (int q4 = 0; q4 < 4; q4++){
          int n = n0 + nf*16 + l16;
          Ts[nf*16 + l16][wave*32 + r2*16 + g*4 + q4] = f2bf(acc[r2][nf][q4] + bia[n]);
        }
    __syncthreads();
    #pragma unroll
    for (int i = 0; i < 8; i++){
      int id = t + i*256;
      int nr = id >> 4, mc = (id & 15)*8;
      *(int4*)(Vt + ((size_t)b*Dd + n0 + nr)*Nn + m0 + mc) = *(int4*)&Ts[nr][mc];
    }
  } else {
    ushort* out = (which==0) ? Qh : Kh;
    float sc = (which==0) ? qscale : 1.0f;
    #pragma unroll
    for (int nf = 0; nf < 8; nf++){
      #pragma unroll
      for (int r2 = 0; r2 < 2; r2++)
        #pragma unroll
        for (int q4 = 0; q4 < 4; q4++){
          int m = m0 + wave*32 + r2*16 + g*4 + q4;   // node
          int n = n0 + nf*16 + l16;                  // out channel
          float val = (acc[r2][nf][q4] + bia[n]) * sc;
          int h = n >> 5, hd = n & 31;
          out[((size_t)(b*Hh + h)*Nn + m)*HDd + hd] = f2bf(val);
        }
    }
  }
}

// ---------------- MFMA attention v3: swapped QK^T + T14 reg-prefetch of K/V/mask ----
__global__ __launch_bounds__(256, 4) void k_attn(const ushort* __restrict__ Qg, const ushort* __restrict__ Kg,
                                              const ushort* __restrict__ Vt, const ushort* __restrict__ Mbits,
                                              ushort* __restrict__ xh){
  __shared__ ushort Ks[KT][40];        // K rows [k][hd]
  __shared__ ushort Vs[HDd][KT+8];     // V^T [hd][k]
  __shared__ ushort Ps[4][16][KT+8];   // per-wave P [q][k]

  int bx = blockIdx.x;
  int bh = bx & 255;
  int qt = bx >> 8;
  int b = bh >> 3, h = bh & 7;
  int t = threadIdx.x, wave = t >> 6, lane = t & 63;
  int g = lane >> 4, l16 = lane & 15;

  const ushort* Qp = Qg + (size_t)bh*Nn*HDd;
  const ushort* Kp = Kg + (size_t)bh*Nn*HDd;
  const ushort* Vp = Vt + (size_t)bh*HDd*Nn;

  int q0 = qt*64 + wave*16;
  bf16x8 qfrag = *(const bf16x8*)(Qp + (size_t)(q0 + l16)*HDd + g*8);
  const ushort* Mrow = Mbits + (size_t)(q0 + l16)*32;   // this lane's mask row

  bf16x8 ones;
  #pragma unroll
  for (int j = 0; j < 8; j++) ones[j] = (short)0x3F80;   // 1.0 bf16

  f32x4 Ofrag[2] = {{0,0,0,0},{0,0,0,0}};
  f32x4 rs = {0,0,0,0};

  // per-thread staging coords (K: 64x32 = 1 int4/thread; V: 32x64 = 1 int4/thread)
  int kr = t >> 2, kc = (t & 3)*8;
  int vr = t >> 3, vc = (t & 7)*8;
  const ushort* Ksrc = Kp + (size_t)kr*HDd + kc;
  const ushort* Vsrc = Vp + (size_t)vr*Nn + vc;

  int4 kreg = *(const int4*)Ksrc;          // tile 0
  int4 vreg = *(const int4*)Vsrc;
  uint2 mwv = *(const uint2*)Mrow;

  for (int kt = 0; kt < Nn; kt += KT){
    *(int4*)&Ks[kr][kc] = kreg;
    *(int4*)&Vs[vr][vc] = vreg;
    // pre-shift mask words by g*4 so per-(f,r) bit position is compile-time
    unsigned w0 = mwv.x >> (g*4), w1 = mwv.y >> (g*4);
    __syncthreads();

    if (kt + KT < Nn){                     // issue next tile's loads; waited at next
      kreg = *(const int4*)(Ksrc + (size_t)(kt + KT)*HDd);   // iteration's ds_write
      vreg = *(const int4*)(Vsrc + (kt + KT));
      mwv  = *(const uint2*)(Mrow + ((kt + KT) >> 4));
    }

    #pragma unroll
    for (int f = 0; f < KT/16; f++){
      bf16x8 kfrag = *(const bf16x8*)&Ks[f*16 + l16][g*8];
      unsigned wf = (f & 2) ? w1 : w0;
      f32x4 ci;
      #pragma unroll
      for (int r = 0; r < 4; r++){
        unsigned bit = (wf >> ((f & 1)*16 + r)) & 1u;          // v_bfe_u32
        ci[r] = __uint_as_float((bit - 1u) & 0xF149F2CAu);     // bit?0.0f:-1e30f
      }
      // swapped: A=K rows, B=Q rows -> D[k=f*16+g*4+r][q=l16]
      f32x4 s = __builtin_amdgcn_mfma_f32_16x16x32_bf16(kfrag, qfrag, ci, 0, 0, 0);
      float e0 = __builtin_exp2f(s[0]);
      float e1 = __builtin_exp2f(s[1]);
      float e2 = __builtin_exp2f(s[2]);
      float e3 = __builtin_exp2f(s[3]);
      unsigned p01, p23;
      asm("v_cvt_pk_bf16_f32 %0, %1, %2" : "=v"(p01) : "v"(e0), "v"(e1));
      asm("v_cvt_pk_bf16_f32 %0, %1, %2" : "=v"(p23) : "v"(e2), "v"(e3));
      uint2 pk; pk.x = p01; pk.y = p23;
      *(uint2*)&Ps[wave][l16][f*16 + g*4] = pk;                // single ds_write_b64
    }
    // no barrier: Ps is wave-private, lgkmcnt orders RAW

    __builtin_amdgcn_s_setprio(1);
    #pragma unroll
    for (int ks = 0; ks < KT/32; ks++){
      bf16x8 af = *(const bf16x8*)&Ps[wave][l16][ks*32 + g*8];
      rs = __builtin_amdgcn_mfma_f32_16x16x32_bf16(af, ones, rs, 0, 0, 0);  // row sums
      #pragma unroll
      for (int nt = 0; nt < 2; nt++){
        bf16x8 vf = *(const bf16x8*)&Vs[nt*16 + l16][ks*32 + g*8];
        Ofrag[nt] = __builtin_amdgcn_mfma_f32_16x16x32_bf16(af, vf, Ofrag[nt], 0, 0, 0);
      }
    }
    __builtin_amdgcn_s_setprio(0);
    __syncthreads();
  }

  float inv[4];
  #pragma unroll
  for (int r = 0; r < 4; r++) inv[r] = 1.0f / rs[r];

  #pragma unroll
  for (int nt = 0; nt < 2; nt++){
    #pragma unroll
    for (int r = 0; r < 4; r++){
      int row = q0 + g*4 + r;
      int col = h*HDd + nt*16 + l16;
      xh[((size_t)b*Nn + row)*Dd + col] = f2bf(Ofrag[nt][r] * inv[r]);
    }
  }
}

// ============ legacy bf16-A 128x64 pieces (k_gemm_o) ============
#define STAGE_A128(srcp, ldK)                                          \
  _Pragma("unroll")                                                    \
  for (int call = 0; call < 4; call++){                                \
    int id_ = t + call*256;                                            \
    int row_ = id_ >> 3, c8_ = (id_ & 7) ^ (row_ & 7);                 \
    load_lds16((srcp) + (size_t)row_*(ldK) + c8_*8,                    \
               As + ((size_t)call*256 + wave*64)*8);                   \
  }

#define STAGE_B64(srcp, ldK)                                           \
  _Pragma("unroll")                                                    \
  for (int call = 0; call < 2; call++){                                \
    int id_ = t + call*256;                                            \
    int row_ = id_ >> 3, c8_ = (id_ & 7) ^ (row_ & 7);                 \
    load_lds16((srcp) + (size_t)row_*(ldK) + c8_*8,                    \
               Bs + ((size_t)call*256 + wave*64)*8);                   \
  }

#define GEMM_COMPUTE()                                                           \
  _Pragma("unroll")                                                              \
  for (int kk = 0; kk < 2; kk++){                                                \
    bf16x8 af[2];                                                                \
    _Pragma("unroll")                                                            \
    for (int r2 = 0; r2 < 2; r2++){                                              \
      int ra_ = wave*32 + r2*16 + l16;                                           \
      af[r2] = *(const bf16x8*)(As + ra_*64 + (((kk<<2)+g) ^ (ra_&7))*8);        \
    }                                                                            \
    _Pragma("unroll")                                                            \
    for (int nf = 0; nf < 4; nf++){                                              \
      int rb_ = nf*16 + l16;                                                     \
      bf16x8 bfr = *(const bf16x8*)(Bs + rb_*64 + (((kk<<2)+g) ^ (rb_&7))*8);    \
      _Pragma("unroll")                                                          \
      for (int r2 = 0; r2 < 2; r2++)                                             \
        acc[r2][nf] = __builtin_amdgcn_mfma_f32_16x16x32_bf16(af[r2], bfr, acc[r2][nf], 0, 0, 0); \
    }                                                                            \
  }

// ---------------- out-projection: C = x@Wo + bo, DMA-staged bf16 MFMA
__global__ __launch_bounds__(256) void k_gemm_o(const ushort* __restrict__ xh,
                                                const ushort* __restrict__ Wto,
                                                const float* __restrict__ bo, float* __restrict__ out){
  __shared__ ushort LB[128*64 + 64*64];
  ushort* As = LB;
  ushort* Bs = LB + 128*64;

  // XCD-aware: 512 blocks; each XCD owns 16 consecutive m-tiles complete
  int bid = blockIdx.x;
  int xcd = bid & 7, j_ = bid >> 3;            // j_ 0..63
  int m0 = (xcd*16 + (j_ >> 2))*128;
  int n0 = (j_ & 3)*64;

  int t = threadIdx.x, wave = t >> 6, lane = t & 63;
  int g = lane >> 4, l16 = lane & 15;

  f32x4 acc[2][4] = {};

  for (int k0 = 0; k0 < Dd; k0 += 64){
    STAGE_A128(xh + (size_t)m0*Dd + k0, Dd);
    STAGE_B64(Wto + (size_t)n0*Dd + k0, Dd);
    __syncthreads();
    GEMM_COMPUTE();
    __syncthreads();
  }

  #pragma unroll
  for (int nf = 0; nf < 4; nf++){
    #pragma unroll
    for (int r2 = 0; r2 < 2; r2++)
      #pragma unroll
      for (int q4 = 0; q4 < 4; q4++){
        int m = m0 + wave*32 + r2*16 + g*4 + q4;
        int n = n0 + nf*16 + l16;
        out[(size_t)m*Dd + n] = acc[r2][nf][q4] + bo[n];
      }
  }
}

// ---------------- launch ----------------
extern "C" void kernel_launch(void* const* d_in, const int* in_sizes, int n_in,
                              void* d_out, int out_size, void* d_ws, size_t ws_size,
                              hipStream_t stream){
  const float* query = (const float*)d_in[0];
  const float* key   = (const float*)d_in[1];
  const float* value = (const float*)d_in[2];
  const int*   ei    = (const int*)  d_in[3];
  const int*   mask  = (const int*)  d_in[4];
  const float* Wq = (const float*)d_in[5];
  const float* bq = (const float*)d_in[6];
  const float* Wk = (const float*)d_in[7];
  const float* bk = (const float*)d_in[8];
  const float* Wv = (const float*)d_in[9];
  const float* bv = (const float*)d_in[10];
  const float* Wo = (const float*)d_in[11];
  const float* bo = (const float*)d_in[12];

  char* ws = (char*)d_ws;
  size_t off = 0;
  auto alloc = [&](size_t bytes)->void*{
    void* p = ws + off;
    off = (off + bytes + 255) & ~(size_t)255;
    return p;
  };
  int*    count  = (int*)   alloc(Nn*4);              // contiguous with S (one memset)
  float*  S      = (float*) alloc((size_t)Nn*Nn*4);
  ushort* Mbits  = (ushort*)alloc((size_t)Nn*32*2);
  ushort* Wtq    = (ushort*)alloc((size_t)Dd*Dd*2);
  ushort* Wtk    = (ushort*)alloc((size_t)Dd*Dd*2);
  ushort* Wtv    = (ushort*)alloc((size_t)Dd*Dd*2);
  ushort* Wto    = (ushort*)alloc((size_t)Dd*Dd*2);
  size_t tszb = (size_t)Bc*Nn*Dd*sizeof(ushort);
  ushort* Ttq = (ushort*)alloc(tszb);
  ushort* Ttk = (ushort*)alloc(tszb);
  ushort* Ttv = (ushort*)alloc(tszb);
  ushort* Qh  = (ushort*)alloc(tszb);
  ushort* Kh  = (ushort*)alloc(tszb);
  ushort* Vt  = (ushort*)alloc(tszb);
  ushort* xh  = (ushort*)alloc(tszb);

  hipMemsetAsync(count, 0, Nn*4 + (size_t)Nn*Nn*4, stream);   // count + S, contiguous

  k_count  <<<Ee/256, 256, 0, stream>>>(ei, count);
  k_scatter<<<Ee/256, 256, 0, stream>>>(ei, count, S);

  dim3 gw(4, 4, 5);   // z=0..3: weight transpose; z=4: mask bit-pack
  k_wt<<<gw, 256, 0, stream>>>(Wq, Wk, Wv, Wo, mask, Wtq, Wtk, Wtv, Wto, Mbits);

  k_proj<<<768, 256, 0, stream>>>(query, key, value, Wtq, Wtk, Wtv, Ttq, Ttk, Ttv);
  k_agge<<<768, 256, 0, stream>>>(S, Ttq, Ttk, Ttv, bq, bk, bv, Qh, Kh, Vt);

  k_attn<<<Bc*Hh*8, 256, 0, stream>>>(Qh, Kh, Vt, Mbits, xh);

  k_gemm_o<<<512, 256, 0, stream>>>(xh, Wto, bo, (float*)d_out);
}

// Round 4
// 187.527 us; speedup vs baseline: 1.0655x; 1.0118x over previous
//
#include <hip/hip_runtime.h>
#include <hip/hip_bf16.h>
#include <math.h>

// Problem constants
#define Bc  32
#define Nn  512
#define Dd  256
#define Hh  8
#define HDd 32
#define Ee  16384
#define KT  64    // attention k-tile

typedef __attribute__((ext_vector_type(8))) short bf16x8;
typedef __attribute__((ext_vector_type(4))) float f32x4;

__device__ inline ushort f2bf(float x){
  union { float f; unsigned u; } v; v.f = x;
  return (ushort)((v.u + 0x7fff + ((v.u >> 16) & 1)) >> 16);   // RNE
}

// async global->LDS DMA, 16B per lane; LDS dest = wave-uniform base + lane*16
__device__ __forceinline__ void load_lds16(const void* g, void* l){
  __builtin_amdgcn_global_load_lds((const __attribute__((address_space(1))) unsigned int*)g,
                                   (__attribute__((address_space(3))) unsigned int*)l, 16, 0, 0);
}

// pack 8 f32 -> bf16x8 via v_cvt_pk_bf16_f32 (RNE, matches f2bf)
__device__ __forceinline__ bf16x8 pack8(f32x4 lo, f32x4 hi){
  union { bf16x8 v; unsigned u[4]; } r;
  asm("v_cvt_pk_bf16_f32 %0, %1, %2" : "=v"(r.u[0]) : "v"(lo[0]), "v"(lo[1]));
  asm("v_cvt_pk_bf16_f32 %0, %1, %2" : "=v"(r.u[1]) : "v"(lo[2]), "v"(lo[3]));
  asm("v_cvt_pk_bf16_f32 %0, %1, %2" : "=v"(r.u[2]) : "v"(hi[0]), "v"(hi[1]));
  asm("v_cvt_pk_bf16_f32 %0, %1, %2" : "=v"(r.u[3]) : "v"(hi[2]), "v"(hi[3]));
  return r.v;
}

// ---------------- W transpose+convert (z<4) + mask bit-pack (z==4) + deg count (z==5)
__global__ __launch_bounds__(256) void k_wt(const float* __restrict__ Wq, const float* __restrict__ Wk,
                                            const float* __restrict__ Wv, const float* __restrict__ Wo,
                                            const int* __restrict__ mask, const int* __restrict__ ei,
                                            ushort* __restrict__ Wtq, ushort* __restrict__ Wtk,
                                            ushort* __restrict__ Wtv, ushort* __restrict__ Wto,
                                            ushort* __restrict__ Mbits, int* __restrict__ count){
  __shared__ float Ls[64][65];
  int mat = blockIdx.z;
  if (mat == 5){
    // degree count: 16 blocks x 256 threads x 4 edges
    int bid = blockIdx.y*4 + blockIdx.x;        // 0..15
    int e0 = bid*1024 + threadIdx.x*4;
    #pragma unroll
    for (int j = 0; j < 4; j++)
      atomicAdd(&count[ei[Ee + e0 + j]], 1);
    return;
  }
  if (mat == 4){
    int bid = blockIdx.y*4 + blockIdx.x;        // 0..15
    int w0 = bid*1024 + threadIdx.x*4;
    #pragma unroll
    for (int j = 0; j < 4; j++){
      int w = w0 + j;
      int row = w >> 5, c0 = (w & 31) << 4;
      unsigned bits = 0;
      #pragma unroll
      for (int i = 0; i < 16; i++)
        bits |= (mask[(size_t)row*Nn + c0 + i] != 0 ? 1u : 0u) << i;
      Mbits[w] = (ushort)bits;
    }
    return;
  }
  const float* Wsrc = (mat==0)?Wq:(mat==1)?Wk:(mat==2)?Wv:Wo;
  ushort* Wt = (mat==0)?Wtq:(mat==1)?Wtk:(mat==2)?Wtv:Wto;
  int k0 = blockIdx.x*64, n0 = blockIdx.y*64;
  int t = threadIdx.x;
  {
    int r = t >> 2, c4 = (t & 3)*16;
    #pragma unroll
    for (int j = 0; j < 16; j += 4)
      *(float4*)&Ls[r][c4+j] = *(const float4*)(Wsrc + (size_t)(k0+r)*Dd + n0 + c4 + j);
  }
  __syncthreads();
  int nr = t >> 2, kc = (t & 3)*16;
  ushort hb[16];
  #pragma unroll
  for (int j = 0; j < 16; j++) hb[j] = f2bf(Ls[kc+j][nr]);
  size_t dst = (size_t)(n0+nr)*Dd + k0 + kc;
  *(int4*)(Wt + dst)     = ((int4*)hb)[0];
  *(int4*)(Wt + dst + 8) = ((int4*)hb)[1];
}

// ============ 128x128-tile GEMM pieces ============
// A(f32): 128 rows x 64 f32 (32KB), 16 chunks/row of 16B; chunk slot p of row r
// holds global chunk p^(r&15). A/B(bf16): 128 rows x 64 bf16 (16KB), 8 chunks/row,
// slot p^(r&7). (swizzle applied on the GLOBAL offset; DMA's LDS side is linear.)

#define STAGE_AF32(srcp, ldK)                                           \
  _Pragma("unroll")                                                     \
  for (int call = 0; call < 8; call++){                                 \
    int id_ = t + call*256;                                             \
    int row_ = id_ >> 4, c16_ = (id_ & 15) ^ (row_ & 15);               \
    load_lds16((srcp) + (size_t)row_*(ldK) + c16_*4,                    \
               AsF + ((size_t)call*256 + wave*64)*4);                   \
  }

#define STAGE_A128(srcp, ldK)                                           \
  _Pragma("unroll")                                                     \
  for (int call = 0; call < 4; call++){                                 \
    int id_ = t + call*256;                                             \
    int row_ = id_ >> 3, c8_ = (id_ & 7) ^ (row_ & 7);                  \
    load_lds16((srcp) + (size_t)row_*(ldK) + c8_*8,                     \
               As + ((size_t)call*256 + wave*64)*8);                    \
  }

#define STAGE_B128(srcp, ldK)                                           \
  _Pragma("unroll")                                                     \
  for (int call = 0; call < 4; call++){                                 \
    int id_ = t + call*256;                                             \
    int row_ = id_ >> 3, c8_ = (id_ & 7) ^ (row_ & 7);                  \
    load_lds16((srcp) + (size_t)row_*(ldK) + c8_*8,                     \
               Bs + ((size_t)call*256 + wave*64)*8);                    \
  }

// f32-A compute (pack8 in-register convert), 8 n-frags
#define GEMM_COMPUTE_F128()                                             \
  _Pragma("unroll")                                                     \
  for (int kk = 0; kk < 2; kk++){                                       \
    bf16x8 af[2];                                                       \
    _Pragma("unroll")                                                   \
    for (int r2 = 0; r2 < 2; r2++){                                     \
      int ra_ = wave*32 + r2*16 + l16;                                  \
      int cb_ = (kk*4 + g)*2;                                           \
      f32x4 lo_ = *(const f32x4*)(AsF + ra_*64 + ((cb_    ) ^ (ra_&15))*4); \
      f32x4 hi_ = *(const f32x4*)(AsF + ra_*64 + ((cb_ + 1) ^ (ra_&15))*4); \
      af[r2] = pack8(lo_, hi_);                                         \
    }                                                                   \
    _Pragma("unroll")                                                   \
    for (int nf = 0; nf < 8; nf++){                                     \
      int rb_ = nf*16 + l16;                                            \
      bf16x8 bfr = *(const bf16x8*)(Bs + rb_*64 + (((kk<<2)+g) ^ (rb_&7))*8); \
      _Pragma("unroll")                                                 \
      for (int r2 = 0; r2 < 2; r2++)                                    \
        acc[r2][nf] = __builtin_amdgcn_mfma_f32_16x16x32_bf16(af[r2], bfr, acc[r2][nf], 0, 0, 0); \
    }                                                                   \
  }

// bf16-A compute, 8 n-frags
#define GEMM_COMPUTE_B128()                                             \
  _Pragma("unroll")                                                     \
  for (int kk = 0; kk < 2; kk++){                                       \
    bf16x8 af[2];                                                       \
    _Pragma("unroll")                                                   \
    for (int r2 = 0; r2 < 2; r2++){                                     \
      int ra_ = wave*32 + r2*16 + l16;                                  \
      af[r2] = *(const bf16x8*)(As + ra_*64 + (((kk<<2)+g) ^ (ra_&7))*8); \
    }                                                                   \
    _Pragma("unroll")                                                   \
    for (int nf = 0; nf < 8; nf++){                                     \
      int rb_ = nf*16 + l16;                                            \
      bf16x8 bfr = *(const bf16x8*)(Bs + rb_*64 + (((kk<<2)+g) ^ (rb_&7))*8); \
      _Pragma("unroll")                                                 \
      for (int r2 = 0; r2 < 2; r2++)                                    \
        acc[r2][nf] = __builtin_amdgcn_mfma_f32_16x16x32_bf16(af[r2], bfr, acc[r2][nf], 0, 0, 0); \
    }                                                                   \
  }

// XCD-aware decode, 768 GEMM blocks (= 96 z-slices x 4 m-tiles x 2 n-tiles); each
// XCD owns 12 z-slices complete; same-z m/n siblings stay on the same XCD (L2 reuse)
#define DECODE_PA128(bidv)                                              \
  int xcd = (bidv) & 7, j_ = (bidv) >> 3;     /* 0..95 */               \
  int z = xcd*12 + (j_ % 12);                                           \
  int rr_ = j_ / 12;                          /* 0..7 */                \
  int m0 = (rr_ >> 1)*128, n0 = (rr_ & 1)*128;                          \
  int which = z >> 5, b = z & 31;

// ---------------- k_proj: T = X@W (no bias), X read DIRECTLY as f32 ----------------
// Blocks 0..63: adjacency scatter (S += norm over edges + self-loop diagonal) —
// runs concurrently with the GEMM blocks, complete at the launch boundary.
// Blocks 64..831: 128x128 GEMM tile; output transposed Tt[b][ch][node].
__global__ __launch_bounds__(256, 3) void k_proj(const float* __restrict__ qI, const float* __restrict__ kI,
                                              const float* __restrict__ vI,
                                              const ushort* __restrict__ Wtq, const ushort* __restrict__ Wtk,
                                              const ushort* __restrict__ Wtv,
                                              const int* __restrict__ ei, const int* __restrict__ count,
                                              float* __restrict__ S,
                                              ushort* __restrict__ Ttq, ushort* __restrict__ Ttk,
                                              ushort* __restrict__ Ttv){
  __shared__ __align__(16) char LB[49152];    // 32KB f32 A + 16KB bf16 B
  float*  AsF = (float*)LB;
  ushort* Bs  = (ushort*)(LB + 32768);

  int bidr = blockIdx.x;
  if (bidr < 64){
    // scatter: 64 blocks x 256 threads = 16384 edges
    int e = bidr*256 + threadIdx.x;
    int s = ei[e], d = ei[Ee + e];
    float w = rsqrtf((1.0f + (float)count[s]) * (1.0f + (float)count[d]));
    atomicAdd(&S[d*Nn + s], w);                               // duplicates accumulate
    if (e < Nn)
      atomicAdd(&S[e*Nn + e], 1.0f/(1.0f + (float)count[e])); // self-loop diagonal
    return;
  }
  int bid = bidr - 64;     // 64%8==0 so bid&7 still matches the physical XCD stripe
  DECODE_PA128(bid);
  const float* X = (which==0)?qI:(which==1)?kI:vI;
  const ushort* Wt = (which==0)?Wtq:(which==1)?Wtk:Wtv;
  ushort*       Tt = (which==0)?Ttq:(which==1)?Ttk:Ttv;

  int t = threadIdx.x, wave = t >> 6, lane = t & 63;
  int g = lane >> 4, l16 = lane & 15;

  f32x4 acc[2][8] = {};

  for (int k0 = 0; k0 < Dd; k0 += 64){
    STAGE_AF32(X + (size_t)(b*Nn + m0)*Dd + k0, Dd);
    STAGE_B128(Wt + (size_t)n0*Dd + k0, Dd);
    __syncthreads();
    GEMM_COMPUTE_F128();
    __syncthreads();
  }

  // transposed epilogue via LDS: Ts[n_local][m_local], 128 x 128 (stride 136)
  ushort (*Ts)[136] = (ushort (*)[136])(void*)LB;
  #pragma unroll
  for (int nf = 0; nf < 8; nf++)
    #pragma unroll
    for (int r2 = 0; r2 < 2; r2++)
      #pragma unroll
      for (int q4 = 0; q4 < 4; q4++)
        Ts[nf*16 + l16][wave*32 + r2*16 + g*4 + q4] = f2bf(acc[r2][nf][q4]);
  __syncthreads();
  #pragma unroll
  for (int i = 0; i < 8; i++){
    int id = t + i*256;
    int nr = id >> 4, mc = (id & 15)*8;
    *(int4*)(Tt + ((size_t)b*Dd + n0 + nr)*Nn + m0 + mc) = *(int4*)&Ts[nr][mc];
  }
}

// ---------------- k_agge: QKV = S @ T + bias (S staged as raw f32)
// Q -> head layout pre-scaled by 1/sqrt(32)*log2(e); K -> head layout; V -> Vt[b][ch][node]
__global__ __launch_bounds__(256, 3) void k_agge(const float* __restrict__ S,
                                              const ushort* __restrict__ Ttq, const ushort* __restrict__ Ttk,
                                              const ushort* __restrict__ Ttv,
                                              const float* __restrict__ bq, const float* __restrict__ bk,
                                              const float* __restrict__ bv,
                                              ushort* __restrict__ Qh, ushort* __restrict__ Kh,
                                              ushort* __restrict__ Vt){
  __shared__ __align__(16) char LB[49152];
  float*  AsF = (float*)LB;
  ushort* Bs  = (ushort*)(LB + 32768);

  DECODE_PA128(blockIdx.x);
  const ushort* Tt  = (which==0)?Ttq:(which==1)?Ttk:Ttv;
  const float*  bia = (which==0)?bq:(which==1)?bk:bv;

  int t = threadIdx.x, wave = t >> 6, lane = t & 63;
  int g = lane >> 4, l16 = lane & 15;

  f32x4 acc[2][8] = {};

  for (int k0 = 0; k0 < Nn; k0 += 64){
    STAGE_AF32(S + (size_t)m0*Nn + k0, Nn);
    STAGE_B128(Tt + ((size_t)b*Dd + n0)*Nn + k0, Nn);
    __syncthreads();
    GEMM_COMPUTE_F128();
    __syncthreads();
  }

  const float qscale = 0.17677669529663687f * 1.4426950408889634f;  // 1/sqrt(32)*log2(e)

  if (which == 2){
    // V: bias then LDS-transpose -> Vt[(b*256 + channel)][node]
    ushort (*Ts)[136] = (ushort (*)[136])(void*)LB;
    #pragma unroll
    for (int nf = 0; nf < 8; nf++)
      #pragma unroll
      for (int r2 = 0; r2 < 2; r2++)
        #pragma unroll
        for (int q4 = 0; q4 < 4; q4++){
          int n = n0 + nf*16 + l16;
          Ts[nf*16 + l16][wave*32 + r2*16 + g*4 + q4] = f2bf(acc[r2][nf][q4] + bia[n]);
        }
    __syncthreads();
    #pragma unroll
    for (int i = 0; i < 8; i++){
      int id = t + i*256;
      int nr = id >> 4, mc = (id & 15)*8;
      *(int4*)(Vt + ((size_t)b*Dd + n0 + nr)*Nn + m0 + mc) = *(int4*)&Ts[nr][mc];
    }
  } else {
    ushort* out = (which==0) ? Qh : Kh;
    float sc = (which==0) ? qscale : 1.0f;
    #pragma unroll
    for (int nf = 0; nf < 8; nf++){
      #pragma unroll
      for (int r2 = 0; r2 < 2; r2++)
        #pragma unroll
        for (int q4 = 0; q4 < 4; q4++){
          int m = m0 + wave*32 + r2*16 + g*4 + q4;   // node
          int n = n0 + nf*16 + l16;                  // out channel
          float val = (acc[r2][nf][q4] + bia[n]) * sc;
          int h = n >> 5, hd = n & 31;
          out[((size_t)(b*Hh + h)*Nn + m)*HDd + hd] = f2bf(val);
        }
    }
  }
}

// ---------------- MFMA attention v4: K/V double-buffer, ONE barrier per tile ----
// Write tile t -> buf[t&1]; barrier; reg-prefetch t+1; compute from buf[t&1]; no
// trailing barrier. Safety: a wave writing buf[(t+1)&1] has passed barrier t, which
// post-dates every other wave's tile t-1 reads of that buffer (program order).
// Ps is wave-private single-buffer: DS ops from one wave complete in order.
__global__ __launch_bounds__(256, 4) void k_attn(const ushort* __restrict__ Qg, const ushort* __restrict__ Kg,
                                              const ushort* __restrict__ Vt, const ushort* __restrict__ Mbits,
                                              ushort* __restrict__ xh){
  __shared__ ushort Ks[2][KT][40];     // K rows [k][hd]
  __shared__ ushort Vs[2][HDd][KT+8];  // V^T [hd][k]
  __shared__ ushort Ps[4][16][KT+8];   // per-wave P [q][k]

  int bx = blockIdx.x;
  int bh = bx & 255;
  int qt = bx >> 8;
  int b = bh >> 3, h = bh & 7;
  int t = threadIdx.x, wave = t >> 6, lane = t & 63;
  int g = lane >> 4, l16 = lane & 15;

  const ushort* Qp = Qg + (size_t)bh*Nn*HDd;
  const ushort* Kp = Kg + (size_t)bh*Nn*HDd;
  const ushort* Vp = Vt + (size_t)bh*HDd*Nn;

  int q0 = qt*64 + wave*16;
  bf16x8 qfrag = *(const bf16x8*)(Qp + (size_t)(q0 + l16)*HDd + g*8);
  const ushort* Mrow = Mbits + (size_t)(q0 + l16)*32;   // this lane's mask row

  bf16x8 ones;
  #pragma unroll
  for (int j = 0; j < 8; j++) ones[j] = (short)0x3F80;   // 1.0 bf16

  f32x4 Ofrag[2] = {{0,0,0,0},{0,0,0,0}};
  f32x4 rs = {0,0,0,0};

  // per-thread staging coords (K: 64x32 = 1 int4/thread; V: 32x64 = 1 int4/thread)
  int kr = t >> 2, kc = (t & 3)*8;
  int vr = t >> 3, vc = (t & 7)*8;
  const ushort* Ksrc = Kp + (size_t)kr*HDd + kc;
  const ushort* Vsrc = Vp + (size_t)vr*Nn + vc;

  int4 kreg = *(const int4*)Ksrc;          // tile 0
  int4 vreg = *(const int4*)Vsrc;
  uint2 mwv = *(const uint2*)Mrow;
  int cur = 0;

  for (int kt = 0; kt < Nn; kt += KT){
    *(int4*)&Ks[cur][kr][kc] = kreg;
    *(int4*)&Vs[cur][vr][vc] = vreg;
    // pre-shift mask words by g*4 so per-(f,r) bit position is compile-time
    unsigned w0 = mwv.x >> (g*4), w1 = mwv.y >> (g*4);
    __syncthreads();

    if (kt + KT < Nn){                     // issue next tile's loads now; latency
      kreg = *(const int4*)(Ksrc + (size_t)(kt + KT)*HDd);   // hides under compute
      vreg = *(const int4*)(Vsrc + (kt + KT));
      mwv  = *(const uint2*)(Mrow + ((kt + KT) >> 4));
    }

    #pragma unroll
    for (int f = 0; f < KT/16; f++){
      bf16x8 kfrag = *(const bf16x8*)&Ks[cur][f*16 + l16][g*8];
      unsigned wf = (f & 2) ? w1 : w0;
      f32x4 ci;
      #pragma unroll
      for (int r = 0; r < 4; r++){
        unsigned bit = (wf >> ((f & 1)*16 + r)) & 1u;          // v_bfe_u32
        ci[r] = __uint_as_float((bit - 1u) & 0xF149F2CAu);     // bit?0.0f:-1e30f
      }
      // swapped: A=K rows, B=Q rows -> D[k=f*16+g*4+r][q=l16]
      f32x4 s = __builtin_amdgcn_mfma_f32_16x16x32_bf16(kfrag, qfrag, ci, 0, 0, 0);
      float e0 = __builtin_exp2f(s[0]);
      float e1 = __builtin_exp2f(s[1]);
      float e2 = __builtin_exp2f(s[2]);
      float e3 = __builtin_exp2f(s[3]);
      unsigned p01, p23;
      asm("v_cvt_pk_bf16_f32 %0, %1, %2" : "=v"(p01) : "v"(e0), "v"(e1));
      asm("v_cvt_pk_bf16_f32 %0, %1, %2" : "=v"(p23) : "v"(e2), "v"(e3));
      uint2 pk; pk.x = p01; pk.y = p23;
      *(uint2*)&Ps[wave][l16][f*16 + g*4] = pk;                // single ds_write_b64
    }
    // no barrier: Ps is wave-private, lgkmcnt orders RAW

    __builtin_amdgcn_s_setprio(1);
    #pragma unroll
    for (int ks = 0; ks < KT/32; ks++){
      bf16x8 af = *(const bf16x8*)&Ps[wave][l16][ks*32 + g*8];
      rs = __builtin_amdgcn_mfma_f32_16x16x32_bf16(af, ones, rs, 0, 0, 0);  // row sums
      #pragma unroll
      for (int nt = 0; nt < 2; nt++){
        bf16x8 vf = *(const bf16x8*)&Vs[cur][nt*16 + l16][ks*32 + g*8];
        Ofrag[nt] = __builtin_amdgcn_mfma_f32_16x16x32_bf16(af, vf, Ofrag[nt], 0, 0, 0);
      }
    }
    __builtin_amdgcn_s_setprio(0);
    cur ^= 1;                              // no trailing barrier (dbuf)
  }

  float inv[4];
  #pragma unroll
  for (int r = 0; r < 4; r++) inv[r] = 1.0f / rs[r];

  #pragma unroll
  for (int nt = 0; nt < 2; nt++){
    #pragma unroll
    for (int r = 0; r < 4; r++){
      int row = q0 + g*4 + r;
      int col = h*HDd + nt*16 + l16;
      xh[((size_t)b*Nn + row)*Dd + col] = f2bf(Ofrag[nt][r] * inv[r]);
    }
  }
}

// ---------------- out-projection: C = x@Wo + bo, 128x128 tile ----------------
__global__ __launch_bounds__(256) void k_gemm_o(const ushort* __restrict__ xh,
                                                const ushort* __restrict__ Wto,
                                                const float* __restrict__ bo, float* __restrict__ out){
  __shared__ ushort As[128*64];   // 16KB
  __shared__ ushort Bs[128*64];   // 16KB

  // 256 blocks = 128 m-tiles x 2 n-tiles; each XCD owns 16 consecutive m-tiles,
  // n-siblings dispatch-adjacent (A-panel L2 reuse)
  int bid = blockIdx.x;
  int xcd = bid & 7, j_ = bid >> 3;            // j_ 0..31
  int m0 = (xcd*16 + (j_ >> 1))*128;
  int n0 = (j_ & 1)*128;

  int t = threadIdx.x, wave = t >> 6, lane = t & 63;
  int g = lane >> 4, l16 = lane & 15;

  f32x4 acc[2][8] = {};

  for (int k0 = 0; k0 < Dd; k0 += 64){
    STAGE_A128(xh + (size_t)m0*Dd + k0, Dd);
    STAGE_B128(Wto + (size_t)n0*Dd + k0, Dd);
    __syncthreads();
    GEMM_COMPUTE_B128();
    __syncthreads();
  }

  #pragma unroll
  for (int nf = 0; nf < 8; nf++){
    #pragma unroll
    for (int r2 = 0; r2 < 2; r2++)
      #pragma unroll
      for (int q4 = 0; q4 < 4; q4++){
        int m = m0 + wave*32 + r2*16 + g*4 + q4;
        int n = n0 + nf*16 + l16;
        out[(size_t)m*Dd + n] = acc[r2][nf][q4] + bo[n];
      }
  }
}

// ---------------- launch ----------------
extern "C" void kernel_launch(void* const* d_in, const int* in_sizes, int n_in,
                              void* d_out, int out_size, void* d_ws, size_t ws_size,
                              hipStream_t stream){
  const float* query = (const float*)d_in[0];
  const float* key   = (const float*)d_in[1];
  const float* value = (const float*)d_in[2];
  const int*   ei    = (const int*)  d_in[3];
  const int*   mask  = (const int*)  d_in[4];
  const float* Wq = (const float*)d_in[5];
  const float* bq = (const float*)d_in[6];
  const float* Wk = (const float*)d_in[7];
  const float* bk = (const float*)d_in[8];
  const float* Wv = (const float*)d_in[9];
  const float* bv = (const float*)d_in[10];
  const float* Wo = (const float*)d_in[11];
  const float* bo = (const float*)d_in[12];

  char* ws = (char*)d_ws;
  size_t off = 0;
  auto alloc = [&](size_t bytes)->void*{
    void* p = ws + off;
    off = (off + bytes + 255) & ~(size_t)255;
    return p;
  };
  int*    count  = (int*)   alloc(Nn*4);              // contiguous with S (one memset)
  float*  S      = (float*) alloc((size_t)Nn*Nn*4);
  ushort* Mbits  = (ushort*)alloc((size_t)Nn*32*2);
  ushort* Wtq    = (ushort*)alloc((size_t)Dd*Dd*2);
  ushort* Wtk    = (ushort*)alloc((size_t)Dd*Dd*2);
  ushort* Wtv    = (ushort*)alloc((size_t)Dd*Dd*2);
  ushort* Wto    = (ushort*)alloc((size_t)Dd*Dd*2);
  size_t tszb = (size_t)Bc*Nn*Dd*sizeof(ushort);
  ushort* Ttq = (ushort*)alloc(tszb);
  ushort* Ttk = (ushort*)alloc(tszb);
  ushort* Ttv = (ushort*)alloc(tszb);
  ushort* Qh  = (ushort*)alloc(tszb);
  ushort* Kh  = (ushort*)alloc(tszb);
  ushort* Vt  = (ushort*)alloc(tszb);
  ushort* xh  = (ushort*)alloc(tszb);

  hipMemsetAsync(count, 0, Nn*4 + (size_t)Nn*Nn*4, stream);   // count + S, contiguous

  dim3 gw(4, 4, 6);   // z<4: weight transpose; z==4: mask bit-pack; z==5: deg count
  k_wt<<<gw, 256, 0, stream>>>(Wq, Wk, Wv, Wo, mask, ei, Wtq, Wtk, Wtv, Wto, Mbits, count);

  // blocks 0..63: edge scatter into S (hides under GEMM); 64..831: X@W tiles
  k_proj<<<832, 256, 0, stream>>>(query, key, value, Wtq, Wtk, Wtv, ei, count, S,
                                  Ttq, Ttk, Ttv);
  k_agge<<<768, 256, 0, stream>>>(S, Ttq, Ttk, Ttv, bq, bk, bv, Qh, Kh, Vt);

  k_attn<<<Bc*Hh*8, 256, 0, stream>>>(Qh, Kh, Vt, Mbits, xh);

  k_gemm_o<<<256, 256, 0, stream>>>(xh, Wto, bo, (float*)d_out);
}